// Round 7
// baseline (349.029 us; speedup 1.0000x reference)
//
#include <hip/hip_runtime.h>
#include <hip/hip_bf16.h>

typedef _Float16 half8 __attribute__((ext_vector_type(8)));
typedef _Float16 half4v __attribute__((ext_vector_type(4)));
typedef float floatx4 __attribute__((ext_vector_type(4)));

#define C_DIM 256
#define M_DIM 512
#define HW 4096
#define TAU 0.0025f

// ---------------- prep: memN = l2norm(relu(relu(mem@w1+b1)@w2+b2)) ----------------
// outputs: mN = fp16 [512][256] (GEMM1 B-operand); mN32 = fp32 [512][256] (gather rows)
__global__ __launch_bounds__(128) void prep_kernel(
    const float* __restrict__ memory, const float* __restrict__ w1,
    const float* __restrict__ b1, const float* __restrict__ w2,
    const float* __restrict__ b2,
    _Float16* __restrict__ mN, float* __restrict__ mN32)
{
  __shared__ float sm[256];
  __shared__ float sh[128];
  __shared__ float s_part[2];
  __shared__ float s_tot;
  const int r = blockIdx.x;
  const int t = threadIdx.x;
  sm[t]       = memory[r * C_DIM + t];
  sm[t + 128] = memory[r * C_DIM + t + 128];
  __syncthreads();
  float acc = b1[t];
#pragma unroll 8
  for (int c = 0; c < 256; ++c) acc = fmaf(sm[c], w1[c * 128 + t], acc);
  sh[t] = fmaxf(acc, 0.f);
  __syncthreads();
  float o0 = b2[t], o1 = b2[t + 128];
#pragma unroll 8
  for (int k = 0; k < 128; ++k) {
    float h = sh[k];
    o0 = fmaf(h, w2[k * 256 + t], o0);
    o1 = fmaf(h, w2[k * 256 + t + 128], o1);
  }
  o0 = fmaxf(o0, 0.f);
  o1 = fmaxf(o1, 0.f);
  float ss = o0 * o0 + o1 * o1;
#pragma unroll
  for (int off = 32; off >= 1; off >>= 1) ss += __shfl_down(ss, off);
  if ((t & 63) == 0) s_part[t >> 6] = ss;
  __syncthreads();
  if (t == 0) s_tot = s_part[0] + s_part[1];
  __syncthreads();
  const float inv = 1.f / fmaxf(sqrtf(s_tot), 1e-12f);
  const float v0 = o0 * inv, v1 = o1 * inv;
  mN[r * C_DIM + t]        = (_Float16)v0;
  mN[r * C_DIM + t + 128]  = (_Float16)v1;
  mN32[r * C_DIM + t]       = v0;
  mN32[r * C_DIM + t + 128] = v1;
}

#define MFMA16(a, b, c) __builtin_amdgcn_mfma_f32_16x16x32_f16(a, b, c, 0, 0, 0)

// ---------------- fused main kernel: 32 pixels per block, 2048 blocks ----------------
// Key structural facts exploited:
//  * att = relu(softmax - tau)/renorm is ~99.99% ZERO (tau is ~4 sigma above the
//    mean softmax prob), so "att @ memN" is a sparse gather of 0-2 rows per pixel,
//    not a GEMM. No attb buffer, no GEMM2 MFMA, exact fp32 epilogue math.
//  * LDS is sized to 48.1 KB on purpose: caps occupancy at 3 blocks/CU = 6 waves/EU,
//    so the compiler's VGPR budget is 85 and GEMM1's B-prefetch regs stay live
//    (at <=40 KB LDS the scheduler targets 8 waves/EU and strips the pipeline - R3).
//  * All gather LOADS are issued after the last barrier and BEFORE any global store,
//    so the in-order vmem FIFO never makes a load wait on a store drain; the only
//    store drain is at endpgm, hidden by the other 2 resident blocks (R6 lesson).
__global__ __launch_bounds__(512, 6) void main_kernel(
    const float* __restrict__ x,
    const _Float16* __restrict__ mN,
    const float* __restrict__ mN32,
    float* __restrict__ out, float* __restrict__ attmap)
{
  __shared__ _Float16 Xh[32][264];      // 16896 B
  __shared__ int      s_lslot[32][120]; // 15360 B   nonzero slot indices per pixel
  __shared__ float    s_lval[32][120];  // 15360 B   nonzero att values per pixel
  __shared__ int      s_cnt[32];
  __shared__ float    s_sumsq[32];
  __shared__ float    s_sum1[32];
  __shared__ float    s_sum2[32];

  const int tid  = threadIdx.x;
  const int wave = tid >> 6;     // 0..7
  const int lane = tid & 63;
  const int q    = lane >> 4;    // quad within wave
  const int c16  = lane & 15;
  const int g    = tid >> 3;     // 0..63: channel quad for phase A
  const int pxq  = tid & 7;      // pixel quad for phase A

  const int blk = blockIdx.x;          // 2048 blocks
  const int img = blk >> 7;            // 128 blocks per image
  const int hw0 = (blk & 127) * 32;
  const float* __restrict__ xb = x + (size_t)img * C_DIM * HW + hw0;

  if (tid < 32) {
    s_sumsq[tid] = 0.f; s_sum1[tid] = 0.f; s_sum2[tid] = 0.f; s_cnt[tid] = 0;
  }
  __syncthreads();  // B0

  // ---- Phase A: float4 loads (4 ch x 4 px per thread), fp16 pack to LDS, sumsq
  {
    floatx4 v[4];
#pragma unroll
    for (int i = 0; i < 4; ++i)
      v[i] = *(const floatx4*)(xb + (size_t)(4 * g + i) * HW + pxq * 4);
    float ps[4];
#pragma unroll
    for (int j = 0; j < 4; ++j) {
      const int p = pxq * 4 + j;
      half4v hv = {(_Float16)v[0][j], (_Float16)v[1][j], (_Float16)v[2][j], (_Float16)v[3][j]};
      *(half4v*)&Xh[p][4 * g] = hv;
      ps[j] = v[0][j] * v[0][j] + v[1][j] * v[1][j] + v[2][j] * v[2][j] + v[3][j] * v[3][j];
    }
#pragma unroll
    for (int off = 8; off < 64; off <<= 1)
#pragma unroll
      for (int j = 0; j < 4; ++j) ps[j] += __shfl_xor(ps[j], off);
    if ((lane >> 3) == 0) {
#pragma unroll
      for (int j = 0; j < 4; ++j) atomicAdd(&s_sumsq[4 * (lane & 7) + j], ps[j]);
    }
  }

  // GEMM1 initial B prefetch before the barrier: L2 latency hides in barrier wait
  const _Float16* bp[4];
#pragma unroll
  for (int nt = 0; nt < 4; ++nt)
    bp[nt] = mN + (size_t)(wave * 64 + nt * 16 + c16) * C_DIM + q * 8;
  half8 bcur[4], bnxt[4];
#pragma unroll
  for (int nt = 0; nt < 4; ++nt) bcur[nt] = *(const half8*)bp[nt];

  __syncthreads();  // B1: Xh + sumsq ready

  // ---- Phase B: GEMM1  S[32][512] = Xh @ mN^T  (fp16 MFMA, 2-stage B prefetch)
  floatx4 acc[2][4];
#pragma unroll
  for (int mt = 0; mt < 2; ++mt)
#pragma unroll
    for (int nt = 0; nt < 4; ++nt) {
      floatx4 z = {0.f, 0.f, 0.f, 0.f};
      acc[mt][nt] = z;
    }
#pragma unroll
  for (int kb = 0; kb < 8; ++kb) {
    if (kb < 7) {
#pragma unroll
      for (int nt = 0; nt < 4; ++nt) bnxt[nt] = *(const half8*)(bp[nt] + (kb + 1) * 32);
    }
    const int k0 = kb * 32 + q * 8;
    const half8 ah0 = *(const half8*)&Xh[c16][k0];
    const half8 ah1 = *(const half8*)&Xh[16 + c16][k0];
#pragma unroll
    for (int nt = 0; nt < 4; ++nt) {
      acc[0][nt] = MFMA16(ah0, bcur[nt], acc[0][nt]);
      acc[1][nt] = MFMA16(ah1, bcur[nt], acc[1][nt]);
    }
#pragma unroll
    for (int nt = 0; nt < 4; ++nt) bcur[nt] = bnxt[nt];
  }

  // ---- Phase C: scale by 1/||x||, exp (cosines in [-1,1], no max shift needed)
  // C/D layout: value (m = mt*16 + q*4 + r, n = wave*64 + nt*16 + c16)
#pragma unroll
  for (int mt = 0; mt < 2; ++mt)
#pragma unroll
    for (int r = 0; r < 4; ++r) {
      const int m = mt * 16 + q * 4 + r;
      const float iv = 1.f / fmaxf(sqrtf(s_sumsq[m]), 1e-12f);
      float s = 0.f;
#pragma unroll
      for (int nt = 0; nt < 4; ++nt) {
        const float e = __expf(acc[mt][nt][r] * iv);
        acc[mt][nt][r] = e;
        s += e;
      }
      s += __shfl_xor(s, 1);
      s += __shfl_xor(s, 2);
      s += __shfl_xor(s, 4);
      s += __shfl_xor(s, 8);
      if (c16 == 0) atomicAdd(&s_sum1[m], s);
    }
  __syncthreads();  // B2: softmax denominators ready

  // t = relu(p - tau); row sum of t
#pragma unroll
  for (int mt = 0; mt < 2; ++mt)
#pragma unroll
    for (int r = 0; r < 4; ++r) {
      const int m = mt * 16 + q * 4 + r;
      const float isum = 1.f / s_sum1[m];
      float s = 0.f;
#pragma unroll
      for (int nt = 0; nt < 4; ++nt) {
        const float tv = fmaxf(acc[mt][nt][r] * isum - TAU, 0.f);
        acc[mt][nt][r] = tv;
        s += tv;
      }
      s += __shfl_xor(s, 1);
      s += __shfl_xor(s, 2);
      s += __shfl_xor(s, 4);
      s += __shfl_xor(s, 8);
      if (c16 == 0) atomicAdd(&s_sum2[m], s);
    }
  __syncthreads();  // B3: shrink sums ready

  // ---- normalize att in regs + emit nonzeros to per-pixel LDS lists
#pragma unroll
  for (int mt = 0; mt < 2; ++mt) {
    float rs[4];
#pragma unroll
    for (int r = 0; r < 4; ++r)
      rs[r] = 1.f / fmaxf(s_sum2[mt * 16 + q * 4 + r], 1e-12f);
#pragma unroll
    for (int nt = 0; nt < 4; ++nt) {
      floatx4 a4 = acc[mt][nt];
      const int n = wave * 64 + nt * 16 + c16;
#pragma unroll
      for (int r = 0; r < 4; ++r) {
        a4[r] *= rs[r];
        if (a4[r] > 0.f) {
          const int m = mt * 16 + q * 4 + r;
          const int idx = atomicAdd(&s_cnt[m], 1);
          if (idx < 120) { s_lslot[m][idx] = n; s_lval[m][idx] = a4[r]; }
        }
      }
      acc[mt][nt] = a4;
    }
  }
  __syncthreads();  // B4: LAST barrier (no vmem outstanding -> free drain)

  // ---- sparse gather: out[px][chc*16..+15] accumulated in regs (fp32 exact).
  // All loads precede all stores below: no load ever waits on a store drain.
  const int px  = tid & 31;
  const int chc = tid >> 5;   // 0..15, 16-channel chunk
  const int cn  = min(s_cnt[px], 120);
  floatx4 f[4] = {{0.f,0.f,0.f,0.f},{0.f,0.f,0.f,0.f},{0.f,0.f,0.f,0.f},{0.f,0.f,0.f,0.f}};
  for (int j = 0; j < cn; ++j) {
    const int slot = s_lslot[px][j];
    const float v  = s_lval[px][j];
    const floatx4* row = (const floatx4*)(mN32 + (size_t)slot * C_DIM + chc * 16);
#pragma unroll
    for (int u = 0; u < 4; ++u) f[u] += v * row[u];
  }

  // ---- att_map stores directly from acc regs (fp32 exact, 4 consecutive px/lane)
#pragma unroll
  for (int mt = 0; mt < 2; ++mt)
#pragma unroll
    for (int nt = 0; nt < 4; ++nt) {
      const int n = wave * 64 + nt * 16 + c16;
      *(floatx4*)(attmap + ((size_t)img * M_DIM + n) * HW + hw0 + mt * 16 + q * 4) =
          acc[mt][nt];
    }

  // ---- out stores from gather regs (lanes 0..31 = consecutive px: coalesced)
#pragma unroll
  for (int cc = 0; cc < 16; ++cc)
    out[((size_t)img * C_DIM + chc * 16 + cc) * HW + hw0 + px] = f[cc >> 2][cc & 3];
}

extern "C" void kernel_launch(void* const* d_in, const int* in_sizes, int n_in,
                              void* d_out, int out_size, void* d_ws, size_t ws_size,
                              hipStream_t stream) {
  (void)in_sizes; (void)n_in; (void)out_size; (void)ws_size;
  const float* x      = (const float*)d_in[0];
  const float* memory = (const float*)d_in[1];
  const float* w1     = (const float*)d_in[2];
  const float* b1     = (const float*)d_in[3];
  const float* w2     = (const float*)d_in[4];
  const float* b2     = (const float*)d_in[5];
  float* out    = (float*)d_out;
  float* attmap = out + (size_t)16 * C_DIM * HW;  // output first, att_map second

  _Float16* mN  = (_Float16*)d_ws;
  float*    mN32 = (float*)((char*)d_ws + (size_t)M_DIM * C_DIM * sizeof(_Float16));

  hipLaunchKernelGGL(prep_kernel, dim3(M_DIM), dim3(128), 0, stream,
                     memory, w1, b1, w2, b2, mN, mN32);
  hipLaunchKernelGGL(main_kernel, dim3(2048), dim3(512), 0, stream,
                     x, mN, mN32, out, attmap);
}

// Round 8
// 338.944 us; speedup vs baseline: 1.0298x; 1.0298x over previous
//
#include <hip/hip_runtime.h>
#include <hip/hip_bf16.h>

typedef _Float16 half8 __attribute__((ext_vector_type(8)));
typedef _Float16 half4v __attribute__((ext_vector_type(4)));
typedef float floatx4 __attribute__((ext_vector_type(4)));

#define C_DIM 256
#define M_DIM 512
#define HW 4096
#define TAU 0.0025f
#define LCAP 120

// ---------------- prep: memN = l2norm(relu(relu(mem@w1+b1)@w2+b2)) ----------------
// outputs: mN = fp16 [512][256] (GEMM1 B-operand); mN32 = fp32 [512][256] (gather rows)
__global__ __launch_bounds__(128) void prep_kernel(
    const float* __restrict__ memory, const float* __restrict__ w1,
    const float* __restrict__ b1, const float* __restrict__ w2,
    const float* __restrict__ b2,
    _Float16* __restrict__ mN, float* __restrict__ mN32)
{
  __shared__ float sm[256];
  __shared__ float sh[128];
  __shared__ float s_part[2];
  __shared__ float s_tot;
  const int r = blockIdx.x;
  const int t = threadIdx.x;
  sm[t]       = memory[r * C_DIM + t];
  sm[t + 128] = memory[r * C_DIM + t + 128];
  __syncthreads();
  float acc = b1[t];
#pragma unroll 8
  for (int c = 0; c < 256; ++c) acc = fmaf(sm[c], w1[c * 128 + t], acc);
  sh[t] = fmaxf(acc, 0.f);
  __syncthreads();
  float o0 = b2[t], o1 = b2[t + 128];
#pragma unroll 8
  for (int k = 0; k < 128; ++k) {
    float h = sh[k];
    o0 = fmaf(h, w2[k * 256 + t], o0);
    o1 = fmaf(h, w2[k * 256 + t + 128], o1);
  }
  o0 = fmaxf(o0, 0.f);
  o1 = fmaxf(o1, 0.f);
  float ss = o0 * o0 + o1 * o1;
#pragma unroll
  for (int off = 32; off >= 1; off >>= 1) ss += __shfl_down(ss, off);
  if ((t & 63) == 0) s_part[t >> 6] = ss;
  __syncthreads();
  if (t == 0) s_tot = s_part[0] + s_part[1];
  __syncthreads();
  const float inv = 1.f / fmaxf(sqrtf(s_tot), 1e-12f);
  const float v0 = o0 * inv, v1 = o1 * inv;
  mN[r * C_DIM + t]        = (_Float16)v0;
  mN[r * C_DIM + t + 128]  = (_Float16)v1;
  mN32[r * C_DIM + t]       = v0;
  mN32[r * C_DIM + t + 128] = v1;
}

#define MFMA16(a, b, c) __builtin_amdgcn_mfma_f32_16x16x32_f16(a, b, c, 0, 0, 0)

// ---------------- fused main kernel: 64 pixels per block, 1024 blocks ----------------
// R4 front-end (64-px tile, 4x4 acc GEMM1 with live B-prefetch — the config where the
// scheduler provably keeps the pipeline: VGPR 64 + 64 AGPR) + R7 sparse epilogue
// (att is ~99.99% zero; "att @ memN" is a 0-2 row gather, not a GEMM).
// List entries packed 4 B ({slot:16, fp16 val:16}) so the 64-px lists fit: LDS = 64 KB
// exactly -> 2 blocks/CU. att_map is stored exact-fp32 from accumulator regs.
// Ordering discipline (R6 lesson): after the last barrier, ALL gather loads are issued
// before ANY global store; outputs are nontemporal (write-once, keep L2 for x/mN).
__global__ __launch_bounds__(512, 4) void main_kernel(
    const float* __restrict__ x,
    const _Float16* __restrict__ mN,
    const float* __restrict__ mN32,
    float* __restrict__ out, float* __restrict__ attmap)
{
  __shared__ _Float16 Xh[64][264];        // 33792 B
  __shared__ unsigned s_list[64][LCAP];   // 30720 B  packed {slot,val16} per pixel
  __shared__ int      s_cnt[64];          //   256 B
  __shared__ float    s_sumsq[64];
  __shared__ float    s_sum1[64];
  __shared__ float    s_sum2[64];         //   768 B   -> total 65536 B

  const int tid  = threadIdx.x;
  const int wave = tid >> 6;     // 0..7
  const int lane = tid & 63;
  const int q    = lane >> 4;    // quad within wave
  const int c16  = lane & 15;
  const int g    = tid >> 3;     // 0..63: channel quad for phase A
  const int pxq  = tid & 7;      // pixel quad (with half-loop) for phase A

  const int blk = blockIdx.x;          // 1024 blocks
  const int img = blk >> 6;            // 64 blocks per image
  const int hw0 = (blk & 63) * 64;
  const float* __restrict__ xb = x + (size_t)img * C_DIM * HW + hw0;

  if (tid < 64) {
    s_sumsq[tid] = 0.f; s_sum1[tid] = 0.f; s_sum2[tid] = 0.f; s_cnt[tid] = 0;
  }
  __syncthreads();  // B0

  // ---- Phase A: float4 loads (2 halves x 4 ch x 4 px per thread), fp16 pack, sumsq
#pragma unroll
  for (int h = 0; h < 2; ++h) {
    floatx4 v[4];
#pragma unroll
    for (int i = 0; i < 4; ++i)
      v[i] = *(const floatx4*)(xb + (size_t)(4 * g + i) * HW + (pxq + 8 * h) * 4);
    float ps[4];
#pragma unroll
    for (int j = 0; j < 4; ++j) {
      const int p = (pxq + 8 * h) * 4 + j;
      half4v hv = {(_Float16)v[0][j], (_Float16)v[1][j], (_Float16)v[2][j], (_Float16)v[3][j]};
      *(half4v*)&Xh[p][4 * g] = hv;
      ps[j] = v[0][j] * v[0][j] + v[1][j] * v[1][j] + v[2][j] * v[2][j] + v[3][j] * v[3][j];
    }
#pragma unroll
    for (int off = 8; off < 64; off <<= 1)
#pragma unroll
      for (int j = 0; j < 4; ++j) ps[j] += __shfl_xor(ps[j], off);
    if ((lane >> 3) == 0) {
#pragma unroll
      for (int j = 0; j < 4; ++j) atomicAdd(&s_sumsq[4 * (lane & 7) + 32 * h + j], ps[j]);
    }
  }

  // GEMM1 initial B prefetch before the barrier: L2 latency hides in barrier wait
  const _Float16* bp[4];
#pragma unroll
  for (int nt = 0; nt < 4; ++nt)
    bp[nt] = mN + (size_t)(wave * 64 + nt * 16 + c16) * C_DIM + q * 8;
  half8 bcur[4], bnxt[4];
#pragma unroll
  for (int nt = 0; nt < 4; ++nt) bcur[nt] = *(const half8*)bp[nt];

  __syncthreads();  // B1: Xh + sumsq ready

  // ---- Phase B: GEMM1  S[64][512] = Xh @ mN^T  (fp16 MFMA, 2-stage B prefetch)
  floatx4 acc[4][4];
#pragma unroll
  for (int mt = 0; mt < 4; ++mt)
#pragma unroll
    for (int nt = 0; nt < 4; ++nt) {
      floatx4 z = {0.f, 0.f, 0.f, 0.f};
      acc[mt][nt] = z;
    }
#pragma unroll
  for (int kb = 0; kb < 8; ++kb) {
    if (kb < 7) {
#pragma unroll
      for (int nt = 0; nt < 4; ++nt) bnxt[nt] = *(const half8*)(bp[nt] + (kb + 1) * 32);
    }
    const int k0 = kb * 32 + q * 8;
    half8 ah[4];
#pragma unroll
    for (int mt = 0; mt < 4; ++mt) ah[mt] = *(const half8*)&Xh[mt * 16 + c16][k0];
#pragma unroll
    for (int nt = 0; nt < 4; ++nt)
#pragma unroll
      for (int mt = 0; mt < 4; ++mt)
        acc[mt][nt] = MFMA16(ah[mt], bcur[nt], acc[mt][nt]);
#pragma unroll
    for (int nt = 0; nt < 4; ++nt) bcur[nt] = bnxt[nt];
  }

  // ---- Phase C: scale by 1/||x||, exp (cosines in [-1,1], no max shift needed)
  // C/D layout: value (m = mt*16 + q*4 + r, n = wave*64 + nt*16 + c16)
#pragma unroll
  for (int mt = 0; mt < 4; ++mt)
#pragma unroll
    for (int r = 0; r < 4; ++r) {
      const int m = mt * 16 + q * 4 + r;
      const float iv = 1.f / fmaxf(sqrtf(s_sumsq[m]), 1e-12f);
      float s = 0.f;
#pragma unroll
      for (int nt = 0; nt < 4; ++nt) {
        const float e = __expf(acc[mt][nt][r] * iv);
        acc[mt][nt][r] = e;
        s += e;
      }
      s += __shfl_xor(s, 1);
      s += __shfl_xor(s, 2);
      s += __shfl_xor(s, 4);
      s += __shfl_xor(s, 8);
      if (c16 == 0) atomicAdd(&s_sum1[m], s);
    }
  __syncthreads();  // B2: softmax denominators ready

  // t = relu(p - tau); row sum of t
#pragma unroll
  for (int mt = 0; mt < 4; ++mt)
#pragma unroll
    for (int r = 0; r < 4; ++r) {
      const int m = mt * 16 + q * 4 + r;
      const float isum = 1.f / s_sum1[m];
      float s = 0.f;
#pragma unroll
      for (int nt = 0; nt < 4; ++nt) {
        const float tv = fmaxf(acc[mt][nt][r] * isum - TAU, 0.f);
        acc[mt][nt][r] = tv;
        s += tv;
      }
      s += __shfl_xor(s, 1);
      s += __shfl_xor(s, 2);
      s += __shfl_xor(s, 4);
      s += __shfl_xor(s, 8);
      if (c16 == 0) atomicAdd(&s_sum2[m], s);
    }
  __syncthreads();  // B3: shrink sums ready

  // ---- normalize att in regs + emit nonzeros to per-pixel packed LDS lists
#pragma unroll
  for (int mt = 0; mt < 4; ++mt) {
    float rs[4];
#pragma unroll
    for (int r = 0; r < 4; ++r)
      rs[r] = 1.f / fmaxf(s_sum2[mt * 16 + q * 4 + r], 1e-12f);
#pragma unroll
    for (int nt = 0; nt < 4; ++nt) {
      floatx4 a4 = acc[mt][nt];
      const unsigned n = wave * 64 + nt * 16 + c16;
#pragma unroll
      for (int r = 0; r < 4; ++r) {
        a4[r] *= rs[r];
        if (a4[r] > 0.f) {
          const int m = mt * 16 + q * 4 + r;
          const int idx = atomicAdd(&s_cnt[m], 1);
          if (idx < LCAP) {
            const unsigned short hb =
                __builtin_bit_cast(unsigned short, (_Float16)a4[r]);
            s_list[m][idx] = (n << 16) | (unsigned)hb;
          }
        }
      }
      acc[mt][nt] = a4;
    }
  }
  __syncthreads();  // B4: LAST barrier (no vmem outstanding -> cheap drain)

  // ---- sparse gather FIRST (all loads precede all stores; R6 lesson).
  // Thread (px = lane, chc = wave) owns 32 channels of one pixel.
  const int px  = lane;
  const int chc = wave;   // 0..7 -> channels [32*chc, 32*chc+32)
  const int cn  = min(s_cnt[px], LCAP);
  floatx4 f[8] = {{0.f,0.f,0.f,0.f},{0.f,0.f,0.f,0.f},{0.f,0.f,0.f,0.f},{0.f,0.f,0.f,0.f},
                  {0.f,0.f,0.f,0.f},{0.f,0.f,0.f,0.f},{0.f,0.f,0.f,0.f},{0.f,0.f,0.f,0.f}};
  for (int j = 0; j < cn; ++j) {
    const unsigned e = s_list[px][j];
    const int slot   = (int)(e >> 16);
    const float v    = (float)__builtin_bit_cast(_Float16, (unsigned short)(e & 0xffffu));
    const floatx4* row = (const floatx4*)(mN32 + (size_t)slot * C_DIM + chc * 32);
#pragma unroll
    for (int u = 0; u < 8; ++u) f[u] += v * row[u];
  }

  // ---- att_map stores directly from acc regs (fp32 exact, 4 consecutive px/lane)
#pragma unroll
  for (int mt = 0; mt < 4; ++mt)
#pragma unroll
    for (int nt = 0; nt < 4; ++nt) {
      const int n = wave * 64 + nt * 16 + c16;
      __builtin_nontemporal_store(
          acc[mt][nt],
          (floatx4*)(attmap + ((size_t)img * M_DIM + n) * HW + hw0 + mt * 16 + q * 4));
    }

  // ---- out stores from gather regs (lanes = consecutive px: 256 B/instr coalesced)
#pragma unroll
  for (int cc = 0; cc < 32; ++cc)
    __builtin_nontemporal_store(
        f[cc >> 2][cc & 3],
        out + ((size_t)img * C_DIM + chc * 32 + cc) * HW + hw0 + px);
}

extern "C" void kernel_launch(void* const* d_in, const int* in_sizes, int n_in,
                              void* d_out, int out_size, void* d_ws, size_t ws_size,
                              hipStream_t stream) {
  (void)in_sizes; (void)n_in; (void)out_size; (void)ws_size;
  const float* x      = (const float*)d_in[0];
  const float* memory = (const float*)d_in[1];
  const float* w1     = (const float*)d_in[2];
  const float* b1     = (const float*)d_in[3];
  const float* w2     = (const float*)d_in[4];
  const float* b2     = (const float*)d_in[5];
  float* out    = (float*)d_out;
  float* attmap = out + (size_t)16 * C_DIM * HW;  // output first, att_map second

  _Float16* mN   = (_Float16*)d_ws;
  float*    mN32 = (float*)((char*)d_ws + (size_t)M_DIM * C_DIM * sizeof(_Float16));

  hipLaunchKernelGGL(prep_kernel, dim3(M_DIM), dim3(128), 0, stream,
                     memory, w1, b1, w2, b2, mN, mN32);
  hipLaunchKernelGGL(main_kernel, dim3(1024), dim3(512), 0, stream,
                     x, mN, mN32, out, attmap);
}

// Round 9
// 326.435 us; speedup vs baseline: 1.0692x; 1.0383x over previous
//
#include <hip/hip_runtime.h>
#include <hip/hip_bf16.h>

typedef _Float16 half8 __attribute__((ext_vector_type(8)));
typedef _Float16 half4v __attribute__((ext_vector_type(4)));
typedef float floatx4 __attribute__((ext_vector_type(4)));

#define C_DIM 256
#define M_DIM 512
#define HW 4096
#define TAU 0.0025f
#define LCAP 96

// ---------------- prep: memN = l2norm(relu(relu(mem@w1+b1)@w2+b2)) ----------------
__global__ __launch_bounds__(128) void prep_kernel(
    const float* __restrict__ memory, const float* __restrict__ w1,
    const float* __restrict__ b1, const float* __restrict__ w2,
    const float* __restrict__ b2,
    _Float16* __restrict__ mN, float* __restrict__ mN32)
{
  __shared__ float sm[256];
  __shared__ float sh[128];
  __shared__ float s_part[2];
  __shared__ float s_tot;
  const int r = blockIdx.x;
  const int t = threadIdx.x;
  sm[t]       = memory[r * C_DIM + t];
  sm[t + 128] = memory[r * C_DIM + t + 128];
  __syncthreads();
  float acc = b1[t];
#pragma unroll 8
  for (int c = 0; c < 256; ++c) acc = fmaf(sm[c], w1[c * 128 + t], acc);
  sh[t] = fmaxf(acc, 0.f);
  __syncthreads();
  float o0 = b2[t], o1 = b2[t + 128];
#pragma unroll 8
  for (int k = 0; k < 128; ++k) {
    float h = sh[k];
    o0 = fmaf(h, w2[k * 256 + t], o0);
    o1 = fmaf(h, w2[k * 256 + t + 128], o1);
  }
  o0 = fmaxf(o0, 0.f);
  o1 = fmaxf(o1, 0.f);
  float ss = o0 * o0 + o1 * o1;
#pragma unroll
  for (int off = 32; off >= 1; off >>= 1) ss += __shfl_down(ss, off);
  if ((t & 63) == 0) s_part[t >> 6] = ss;
  __syncthreads();
  if (t == 0) s_tot = s_part[0] + s_part[1];
  __syncthreads();
  const float inv = 1.f / fmaxf(sqrtf(s_tot), 1e-12f);
  const float v0 = o0 * inv, v1 = o1 * inv;
  mN[r * C_DIM + t]        = (_Float16)v0;
  mN[r * C_DIM + t + 128]  = (_Float16)v1;
  mN32[r * C_DIM + t]       = v0;
  mN32[r * C_DIM + t + 128] = v1;
}

// ---------------- zero_att: contiguous zero-fill of att_map (134 MB @ fill speed) ----
// att_map is ~99.99% zeros; writing them contiguously here costs ~21 us instead of
// the 134 MB strided-256B scatter that capped main at ~2.4 TB/s effective.
__global__ __launch_bounds__(256) void zero_kernel(float* __restrict__ p)
{
  const size_t n4 = (size_t)16 * M_DIM * HW / 4;  // float4 count
  size_t i = (size_t)blockIdx.x * 256 + threadIdx.x;
  const size_t stride = (size_t)gridDim.x * 256;
  const floatx4 z = {0.f, 0.f, 0.f, 0.f};
  for (; i < n4; i += stride) ((floatx4*)p)[i] = z;
}

#define MFMA16(a, b, c) __builtin_amdgcn_mfma_f32_16x16x32_f16(a, b, c, 0, 0, 0)

// ---------------- fused main kernel: 64 pixels per block, 1024 blocks ----------------
// R8 front-end (proven live B-prefetch: VGPR 64 + 64 AGPR at 2 blocks/CU) with the
// att_map bulk store REPLACED by an inline sparse fp32 scatter (~0.045 stores/lane)
// over the pre-zeroed buffer. Main's write traffic: 201 MB -> 67 MB (out only).
// LDS = 70 KB (Xh + fp32 lists) keeps the 2-blocks/CU ceiling that protects the
// prefetch registers. Plain stores everywhere (R8: nontemporal inflated WRITE +50MB).
__global__ __launch_bounds__(512, 4) void main_kernel(
    const float* __restrict__ x,
    const _Float16* __restrict__ mN,
    const float* __restrict__ mN32,
    float* __restrict__ out, float* __restrict__ attmap)
{
  __shared__ _Float16       Xh[64][264];      // 33792 B
  __shared__ unsigned short s_lslot[64][LCAP];// 12288 B
  __shared__ float          s_lval[64][LCAP]; // 24576 B
  __shared__ int      s_cnt[64];
  __shared__ float    s_sumsq[64];
  __shared__ float    s_sum1[64];
  __shared__ float    s_sum2[64];

  const int tid  = threadIdx.x;
  const int wave = tid >> 6;     // 0..7
  const int lane = tid & 63;
  const int q    = lane >> 4;    // quad within wave
  const int c16  = lane & 15;
  const int g    = tid >> 3;     // 0..63: channel quad for phase A
  const int pxq  = tid & 7;      // pixel quad (with half-loop) for phase A

  const int blk = blockIdx.x;          // 1024 blocks
  const int img = blk >> 6;            // 64 blocks per image
  const int hw0 = (blk & 63) * 64;
  const float* __restrict__ xb = x + (size_t)img * C_DIM * HW + hw0;

  if (tid < 64) {
    s_sumsq[tid] = 0.f; s_sum1[tid] = 0.f; s_sum2[tid] = 0.f; s_cnt[tid] = 0;
  }
  __syncthreads();  // B0

  // ---- Phase A: float4 loads (2 halves x 4 ch x 4 px per thread), fp16 pack, sumsq
#pragma unroll
  for (int h = 0; h < 2; ++h) {
    floatx4 v[4];
#pragma unroll
    for (int i = 0; i < 4; ++i)
      v[i] = *(const floatx4*)(xb + (size_t)(4 * g + i) * HW + (pxq + 8 * h) * 4);
    float ps[4];
#pragma unroll
    for (int j = 0; j < 4; ++j) {
      const int p = (pxq + 8 * h) * 4 + j;
      half4v hv = {(_Float16)v[0][j], (_Float16)v[1][j], (_Float16)v[2][j], (_Float16)v[3][j]};
      *(half4v*)&Xh[p][4 * g] = hv;
      ps[j] = v[0][j] * v[0][j] + v[1][j] * v[1][j] + v[2][j] * v[2][j] + v[3][j] * v[3][j];
    }
#pragma unroll
    for (int off = 8; off < 64; off <<= 1)
#pragma unroll
      for (int j = 0; j < 4; ++j) ps[j] += __shfl_xor(ps[j], off);
    if ((lane >> 3) == 0) {
#pragma unroll
      for (int j = 0; j < 4; ++j) atomicAdd(&s_sumsq[4 * (lane & 7) + 32 * h + j], ps[j]);
    }
  }

  // GEMM1 initial B prefetch before the barrier: L2 latency hides in barrier wait
  const _Float16* bp[4];
#pragma unroll
  for (int nt = 0; nt < 4; ++nt)
    bp[nt] = mN + (size_t)(wave * 64 + nt * 16 + c16) * C_DIM + q * 8;
  half8 bcur[4], bnxt[4];
#pragma unroll
  for (int nt = 0; nt < 4; ++nt) bcur[nt] = *(const half8*)bp[nt];

  __syncthreads();  // B1: Xh + sumsq ready

  // ---- Phase B: GEMM1  S[64][512] = Xh @ mN^T  (fp16 MFMA, 2-stage B prefetch)
  floatx4 acc[4][4];
#pragma unroll
  for (int mt = 0; mt < 4; ++mt)
#pragma unroll
    for (int nt = 0; nt < 4; ++nt) {
      floatx4 z = {0.f, 0.f, 0.f, 0.f};
      acc[mt][nt] = z;
    }
#pragma unroll
  for (int kb = 0; kb < 8; ++kb) {
    if (kb < 7) {
#pragma unroll
      for (int nt = 0; nt < 4; ++nt) bnxt[nt] = *(const half8*)(bp[nt] + (kb + 1) * 32);
    }
    const int k0 = kb * 32 + q * 8;
    half8 ah[4];
#pragma unroll
    for (int mt = 0; mt < 4; ++mt) ah[mt] = *(const half8*)&Xh[mt * 16 + c16][k0];
#pragma unroll
    for (int nt = 0; nt < 4; ++nt)
#pragma unroll
      for (int mt = 0; mt < 4; ++mt)
        acc[mt][nt] = MFMA16(ah[mt], bcur[nt], acc[mt][nt]);
#pragma unroll
    for (int nt = 0; nt < 4; ++nt) bcur[nt] = bnxt[nt];
  }

  // ---- Phase C: scale by 1/||x||, exp (cosines in [-1,1], no max shift needed)
  // C/D layout: value (m = mt*16 + q*4 + r, n = wave*64 + nt*16 + c16)
#pragma unroll
  for (int mt = 0; mt < 4; ++mt)
#pragma unroll
    for (int r = 0; r < 4; ++r) {
      const int m = mt * 16 + q * 4 + r;
      const float iv = 1.f / fmaxf(sqrtf(s_sumsq[m]), 1e-12f);
      float s = 0.f;
#pragma unroll
      for (int nt = 0; nt < 4; ++nt) {
        const float e = __expf(acc[mt][nt][r] * iv);
        acc[mt][nt][r] = e;
        s += e;
      }
      s += __shfl_xor(s, 1);
      s += __shfl_xor(s, 2);
      s += __shfl_xor(s, 4);
      s += __shfl_xor(s, 8);
      if (c16 == 0) atomicAdd(&s_sum1[m], s);
    }
  __syncthreads();  // B2: softmax denominators ready

  // t = relu(p - tau); row sum of t
#pragma unroll
  for (int mt = 0; mt < 4; ++mt)
#pragma unroll
    for (int r = 0; r < 4; ++r) {
      const int m = mt * 16 + q * 4 + r;
      const float isum = 1.f / s_sum1[m];
      float s = 0.f;
#pragma unroll
      for (int nt = 0; nt < 4; ++nt) {
        const float tv = fmaxf(acc[mt][nt][r] * isum - TAU, 0.f);
        acc[mt][nt][r] = tv;
        s += tv;
      }
      s += __shfl_xor(s, 1);
      s += __shfl_xor(s, 2);
      s += __shfl_xor(s, 4);
      s += __shfl_xor(s, 8);
      if (c16 == 0) atomicAdd(&s_sum2[m], s);
    }
  __syncthreads();  // B3: shrink sums ready

  // ---- normalize att in regs; emit nonzeros to per-pixel lists AND scatter the
  //      (rare, ~0.045/lane) fp32 values straight into the pre-zeroed att_map.
#pragma unroll
  for (int mt = 0; mt < 4; ++mt) {
    float rs[4];
#pragma unroll
    for (int r = 0; r < 4; ++r)
      rs[r] = 1.f / fmaxf(s_sum2[mt * 16 + q * 4 + r], 1e-12f);
#pragma unroll
    for (int nt = 0; nt < 4; ++nt) {
      floatx4 a4 = acc[mt][nt];
      const unsigned n = wave * 64 + nt * 16 + c16;
#pragma unroll
      for (int r = 0; r < 4; ++r) {
        a4[r] *= rs[r];
        if (a4[r] > 0.f) {
          const int m = mt * 16 + q * 4 + r;
          const int idx = atomicAdd(&s_cnt[m], 1);
          if (idx < LCAP) {
            s_lslot[m][idx] = (unsigned short)n;
            s_lval[m][idx]  = a4[r];
          }
          attmap[((size_t)img * M_DIM + n) * HW + hw0 + m] = a4[r];
        }
      }
    }
  }
  __syncthreads();  // B4: lists ready (few outstanding stores -> cheap drain)

  // ---- sparse gather: thread (px = lane, chc = wave) owns 32 channels of one pixel.
  // All loads precede all stores (R6 lesson).
  const int px  = lane;
  const int chc = wave;   // 0..7 -> channels [32*chc, 32*chc+32)
  const int cn  = min(s_cnt[px], LCAP);
  floatx4 f[8] = {{0.f,0.f,0.f,0.f},{0.f,0.f,0.f,0.f},{0.f,0.f,0.f,0.f},{0.f,0.f,0.f,0.f},
                  {0.f,0.f,0.f,0.f},{0.f,0.f,0.f,0.f},{0.f,0.f,0.f,0.f},{0.f,0.f,0.f,0.f}};
  for (int j = 0; j < cn; ++j) {
    const int slot  = s_lslot[px][j];
    const float v   = s_lval[px][j];
    const floatx4* row = (const floatx4*)(mN32 + (size_t)slot * C_DIM + chc * 32);
#pragma unroll
    for (int u = 0; u < 8; ++u) f[u] += v * row[u];
  }

  // ---- out stores (lanes = consecutive px: 256 B/instr coalesced)
#pragma unroll
  for (int cc = 0; cc < 32; ++cc)
    out[((size_t)img * C_DIM + chc * 32 + cc) * HW + hw0 + px] = f[cc >> 2][cc & 3];
}

extern "C" void kernel_launch(void* const* d_in, const int* in_sizes, int n_in,
                              void* d_out, int out_size, void* d_ws, size_t ws_size,
                              hipStream_t stream) {
  (void)in_sizes; (void)n_in; (void)out_size; (void)ws_size;
  const float* x      = (const float*)d_in[0];
  const float* memory = (const float*)d_in[1];
  const float* w1     = (const float*)d_in[2];
  const float* b1     = (const float*)d_in[3];
  const float* w2     = (const float*)d_in[4];
  const float* b2     = (const float*)d_in[5];
  float* out    = (float*)d_out;
  float* attmap = out + (size_t)16 * C_DIM * HW;  // output first, att_map second

  _Float16* mN   = (_Float16*)d_ws;
  float*    mN32 = (float*)((char*)d_ws + (size_t)M_DIM * C_DIM * sizeof(_Float16));

  hipLaunchKernelGGL(prep_kernel, dim3(M_DIM), dim3(128), 0, stream,
                     memory, w1, b1, w2, b2, mN, mN32);
  hipLaunchKernelGGL(zero_kernel, dim3(2048), dim3(256), 0, stream, attmap);
  hipLaunchKernelGGL(main_kernel, dim3(1024), dim3(512), 0, stream,
                     x, mN, mN32, out, attmap);
}

// Round 10
// 325.265 us; speedup vs baseline: 1.0731x; 1.0036x over previous
//
#include <hip/hip_runtime.h>
#include <hip/hip_bf16.h>

typedef _Float16 half8 __attribute__((ext_vector_type(8)));
typedef _Float16 half4v __attribute__((ext_vector_type(4)));
typedef float floatx4 __attribute__((ext_vector_type(4)));

#define C_DIM 256
#define M_DIM 512
#define HW 4096
#define TAU 0.0025f
#define LCAP 96

// ---------------- prep: memN = l2norm(relu(relu(mem@w1+b1)@w2+b2)) ----------------
// Also zero-fills att_map (134 MB, contiguous, ~21 us BW-bound) fused here so the
// MLP VALU work rides under the write stream and we save one kernel launch.
__global__ __launch_bounds__(128) void prep_kernel(
    const float* __restrict__ memory, const float* __restrict__ w1,
    const float* __restrict__ b1, const float* __restrict__ w2,
    const float* __restrict__ b2,
    _Float16* __restrict__ mN, float* __restrict__ mN32,
    float* __restrict__ attmap)
{
  __shared__ float sm[256];
  __shared__ float sh[128];
  __shared__ float s_part[2];
  __shared__ float s_tot;
  const int r = blockIdx.x;
  const int t = threadIdx.x;

  // ---- att_map zero-fill: 512 blocks x 128 thr, 128 float4 each, coalesced
  {
    const floatx4 z = {0.f, 0.f, 0.f, 0.f};
    floatx4* p4 = (floatx4*)attmap;
    size_t i = (size_t)r * 128 + t;           // 65536 threads
#pragma unroll 4
    for (int k = 0; k < 128; ++k) { p4[i] = z; i += 65536; }
  }

  sm[t]       = memory[r * C_DIM + t];
  sm[t + 128] = memory[r * C_DIM + t + 128];
  __syncthreads();
  float acc = b1[t];
#pragma unroll 8
  for (int c = 0; c < 256; ++c) acc = fmaf(sm[c], w1[c * 128 + t], acc);
  sh[t] = fmaxf(acc, 0.f);
  __syncthreads();
  float o0 = b2[t], o1 = b2[t + 128];
#pragma unroll 8
  for (int k = 0; k < 128; ++k) {
    float h = sh[k];
    o0 = fmaf(h, w2[k * 256 + t], o0);
    o1 = fmaf(h, w2[k * 256 + t + 128], o1);
  }
  o0 = fmaxf(o0, 0.f);
  o1 = fmaxf(o1, 0.f);
  float ss = o0 * o0 + o1 * o1;
#pragma unroll
  for (int off = 32; off >= 1; off >>= 1) ss += __shfl_down(ss, off);
  if ((t & 63) == 0) s_part[t >> 6] = ss;
  __syncthreads();
  if (t == 0) s_tot = s_part[0] + s_part[1];
  __syncthreads();
  const float inv = 1.f / fmaxf(sqrtf(s_tot), 1e-12f);
  const float v0 = o0 * inv, v1 = o1 * inv;
  mN[r * C_DIM + t]        = (_Float16)v0;
  mN[r * C_DIM + t + 128]  = (_Float16)v1;
  mN32[r * C_DIM + t]       = v0;
  mN32[r * C_DIM + t + 128] = v1;
}

#define MFMA16(a, b, c) __builtin_amdgcn_mfma_f32_16x16x32_f16(a, b, c, 0, 0, 0)

// ---------------- fused main kernel: 64 pixels per block, 1024 blocks ----------------
// Proven R9 structure: 64-px tile, 4x4 acc GEMM1 with live B-prefetch (VGPR 64 +
// 64 AGPR = the 2-blocks/CU register tier; 3 blocks/CU is arithmetically impossible
// with a 64-reg accumulator, so this is the occupancy/ILP optimum for this shape).
// att is ~99.99% zero -> sparse epilogue: inline fp32 scatter into pre-zeroed att_map,
// per-pixel LDS lists feed a 0-2 row gather for out. R10 delta: out stores are
// 8x float4/thread (4 px x 8 ch ownership) instead of 32 scalar dwords.
__global__ __launch_bounds__(512, 4) void main_kernel(
    const float* __restrict__ x,
    const _Float16* __restrict__ mN,
    const float* __restrict__ mN32,
    float* __restrict__ out, float* __restrict__ attmap)
{
  __shared__ _Float16       Xh[64][264];      // 33792 B
  __shared__ unsigned short s_lslot[64][LCAP];// 12288 B
  __shared__ float          s_lval[64][LCAP]; // 24576 B
  __shared__ int      s_cnt[64];
  __shared__ float    s_sumsq[64];
  __shared__ float    s_sum1[64];
  __shared__ float    s_sum2[64];

  const int tid  = threadIdx.x;
  const int wave = tid >> 6;     // 0..7
  const int lane = tid & 63;
  const int q    = lane >> 4;    // quad within wave
  const int c16  = lane & 15;
  const int g    = tid >> 3;     // 0..63: channel quad for phase A
  const int pxq  = tid & 7;      // pixel quad (with half-loop) for phase A

  const int blk = blockIdx.x;          // 1024 blocks
  const int img = blk >> 6;            // 64 blocks per image
  const int hw0 = (blk & 63) * 64;
  const float* __restrict__ xb = x + (size_t)img * C_DIM * HW + hw0;

  if (tid < 64) {
    s_sumsq[tid] = 0.f; s_sum1[tid] = 0.f; s_sum2[tid] = 0.f; s_cnt[tid] = 0;
  }
  __syncthreads();  // B0

  // ---- Phase A: float4 loads (2 halves x 4 ch x 4 px per thread), fp16 pack, sumsq
#pragma unroll
  for (int h = 0; h < 2; ++h) {
    floatx4 v[4];
#pragma unroll
    for (int i = 0; i < 4; ++i)
      v[i] = *(const floatx4*)(xb + (size_t)(4 * g + i) * HW + (pxq + 8 * h) * 4);
    float ps[4];
#pragma unroll
    for (int j = 0; j < 4; ++j) {
      const int p = (pxq + 8 * h) * 4 + j;
      half4v hv = {(_Float16)v[0][j], (_Float16)v[1][j], (_Float16)v[2][j], (_Float16)v[3][j]};
      *(half4v*)&Xh[p][4 * g] = hv;
      ps[j] = v[0][j] * v[0][j] + v[1][j] * v[1][j] + v[2][j] * v[2][j] + v[3][j] * v[3][j];
    }
#pragma unroll
    for (int off = 8; off < 64; off <<= 1)
#pragma unroll
      for (int j = 0; j < 4; ++j) ps[j] += __shfl_xor(ps[j], off);
    if ((lane >> 3) == 0) {
#pragma unroll
      for (int j = 0; j < 4; ++j) atomicAdd(&s_sumsq[4 * (lane & 7) + 32 * h + j], ps[j]);
    }
  }

  // GEMM1 initial B prefetch before the barrier: L2 latency hides in barrier wait
  const _Float16* bp[4];
#pragma unroll
  for (int nt = 0; nt < 4; ++nt)
    bp[nt] = mN + (size_t)(wave * 64 + nt * 16 + c16) * C_DIM + q * 8;
  half8 bcur[4], bnxt[4];
#pragma unroll
  for (int nt = 0; nt < 4; ++nt) bcur[nt] = *(const half8*)bp[nt];

  __syncthreads();  // B1: Xh + sumsq ready

  // ---- Phase B: GEMM1  S[64][512] = Xh @ mN^T  (fp16 MFMA, 2-stage B prefetch)
  floatx4 acc[4][4];
#pragma unroll
  for (int mt = 0; mt < 4; ++mt)
#pragma unroll
    for (int nt = 0; nt < 4; ++nt) {
      floatx4 z = {0.f, 0.f, 0.f, 0.f};
      acc[mt][nt] = z;
    }
#pragma unroll
  for (int kb = 0; kb < 8; ++kb) {
    if (kb < 7) {
#pragma unroll
      for (int nt = 0; nt < 4; ++nt) bnxt[nt] = *(const half8*)(bp[nt] + (kb + 1) * 32);
    }
    const int k0 = kb * 32 + q * 8;
    half8 ah[4];
#pragma unroll
    for (int mt = 0; mt < 4; ++mt) ah[mt] = *(const half8*)&Xh[mt * 16 + c16][k0];
#pragma unroll
    for (int nt = 0; nt < 4; ++nt)
#pragma unroll
      for (int mt = 0; mt < 4; ++mt)
        acc[mt][nt] = MFMA16(ah[mt], bcur[nt], acc[mt][nt]);
#pragma unroll
    for (int nt = 0; nt < 4; ++nt) bcur[nt] = bnxt[nt];
  }

  // ---- Phase C: scale by 1/||x||, exp (cosines in [-1,1], no max shift needed)
  // C/D layout: value (m = mt*16 + q*4 + r, n = wave*64 + nt*16 + c16)
#pragma unroll
  for (int mt = 0; mt < 4; ++mt)
#pragma unroll
    for (int r = 0; r < 4; ++r) {
      const int m = mt * 16 + q * 4 + r;
      const float iv = 1.f / fmaxf(sqrtf(s_sumsq[m]), 1e-12f);
      float s = 0.f;
#pragma unroll
      for (int nt = 0; nt < 4; ++nt) {
        const float e = __expf(acc[mt][nt][r] * iv);
        acc[mt][nt][r] = e;
        s += e;
      }
      s += __shfl_xor(s, 1);
      s += __shfl_xor(s, 2);
      s += __shfl_xor(s, 4);
      s += __shfl_xor(s, 8);
      if (c16 == 0) atomicAdd(&s_sum1[m], s);
    }
  __syncthreads();  // B2: softmax denominators ready

  // t = relu(p - tau); row sum of t
#pragma unroll
  for (int mt = 0; mt < 4; ++mt)
#pragma unroll
    for (int r = 0; r < 4; ++r) {
      const int m = mt * 16 + q * 4 + r;
      const float isum = 1.f / s_sum1[m];
      float s = 0.f;
#pragma unroll
      for (int nt = 0; nt < 4; ++nt) {
        const float tv = fmaxf(acc[mt][nt][r] * isum - TAU, 0.f);
        acc[mt][nt][r] = tv;
        s += tv;
      }
      s += __shfl_xor(s, 1);
      s += __shfl_xor(s, 2);
      s += __shfl_xor(s, 4);
      s += __shfl_xor(s, 8);
      if (c16 == 0) atomicAdd(&s_sum2[m], s);
    }
  __syncthreads();  // B3: shrink sums ready

  // ---- normalize att in regs; emit nonzeros to per-pixel lists AND scatter the
  //      (rare, ~0.045/lane) fp32 values straight into the pre-zeroed att_map.
#pragma unroll
  for (int mt = 0; mt < 4; ++mt) {
    float rs[4];
#pragma unroll
    for (int r = 0; r < 4; ++r)
      rs[r] = 1.f / fmaxf(s_sum2[mt * 16 + q * 4 + r], 1e-12f);
#pragma unroll
    for (int nt = 0; nt < 4; ++nt) {
      floatx4 a4 = acc[mt][nt];
      const unsigned n = wave * 64 + nt * 16 + c16;
#pragma unroll
      for (int r = 0; r < 4; ++r) {
        a4[r] *= rs[r];
        if (a4[r] > 0.f) {
          const int m = mt * 16 + q * 4 + r;
          const int idx = atomicAdd(&s_cnt[m], 1);
          if (idx < LCAP) {
            s_lslot[m][idx] = (unsigned short)n;
            s_lval[m][idx]  = a4[r];
          }
          attmap[((size_t)img * M_DIM + n) * HW + hw0 + m] = a4[r];
        }
      }
    }
  }
  __syncthreads();  // B4: lists ready (few outstanding stores -> cheap drain)

  // ---- sparse gather: thread owns 4 consecutive pixels x 8 channels.
  // All loads precede all stores (R6 lesson).
  const int px4 = (tid & 15) * 4;   // pixels px4..px4+3
  const int chg = tid >> 4;         // 0..31 -> channels [8*chg, 8*chg+8)
  floatx4 f[8] = {{0.f,0.f,0.f,0.f},{0.f,0.f,0.f,0.f},{0.f,0.f,0.f,0.f},{0.f,0.f,0.f,0.f},
                  {0.f,0.f,0.f,0.f},{0.f,0.f,0.f,0.f},{0.f,0.f,0.f,0.f},{0.f,0.f,0.f,0.f}};
#pragma unroll
  for (int p = 0; p < 4; ++p) {
    const int cn = min(s_cnt[px4 + p], LCAP);
    for (int j = 0; j < cn; ++j) {
      const int slot  = s_lslot[px4 + p][j];
      const float v   = s_lval[px4 + p][j];
      const floatx4* row = (const floatx4*)(mN32 + (size_t)slot * C_DIM + chg * 8);
      const floatx4 r0 = row[0], r1 = row[1];
      f[0][p] += v * r0[0]; f[1][p] += v * r0[1];
      f[2][p] += v * r0[2]; f[3][p] += v * r0[3];
      f[4][p] += v * r1[0]; f[5][p] += v * r1[1];
      f[6][p] += v * r1[2]; f[7][p] += v * r1[3];
    }
  }

  // ---- out stores: float4 per (channel, 4-px group); 16 lanes x 16 B = 256 B/instr
#pragma unroll
  for (int c = 0; c < 8; ++c)
    *(floatx4*)(out + ((size_t)img * C_DIM + chg * 8 + c) * HW + hw0 + px4) = f[c];
}

extern "C" void kernel_launch(void* const* d_in, const int* in_sizes, int n_in,
                              void* d_out, int out_size, void* d_ws, size_t ws_size,
                              hipStream_t stream) {
  (void)in_sizes; (void)n_in; (void)out_size; (void)ws_size;
  const float* x      = (const float*)d_in[0];
  const float* memory = (const float*)d_in[1];
  const float* w1     = (const float*)d_in[2];
  const float* b1     = (const float*)d_in[3];
  const float* w2     = (const float*)d_in[4];
  const float* b2     = (const float*)d_in[5];
  float* out    = (float*)d_out;
  float* attmap = out + (size_t)16 * C_DIM * HW;  // output first, att_map second

  _Float16* mN   = (_Float16*)d_ws;
  float*    mN32 = (float*)((char*)d_ws + (size_t)M_DIM * C_DIM * sizeof(_Float16));

  hipLaunchKernelGGL(prep_kernel, dim3(M_DIM), dim3(128), 0, stream,
                     memory, w1, b1, w2, b2, mN, mN32, attmap);
  hipLaunchKernelGGL(main_kernel, dim3(1024), dim3(512), 0, stream,
                     x, mN, mN32, out, attmap);
}